// Round 1
// baseline (1472.107 us; speedup 1.0000x reference)
//
#include <hip/hip_runtime.h>

// SparseEncoder: 4096 tokens, d_model=1024, d_concepts=16384, k=32. f32 in/out.
//
// R7 pipeline:
//   1) split:  act,Wenc f32 -> bf16; also zeroes per-token candidate counters
//   2) gemm_bf16 (per 1024-token chunk): pre_bf16 = bf16(A@B^T + bias);
//      m97-style global_load_lds width=16 staging (unpadded 128x32 tiles).
//      NEW: epilogue appends candidates (bf16 value >= 2.0) to per-token
//      global lists as packed (okey16<<14)|idx with an atomic counter.
//   3) cand: fast path = exact top-40-by-key rank-select over the per-token
//      list in LDS (deterministic, no scans). Fallback (count<40 or >1024):
//      original 2x8-bit radix over the pre row with >=0.5 floor.
//   4) transpose: W_emb f32 -> WT bf16 (aliases Bhi after last gemm)
//   5) refine_decode: exact f64 dots for 40 cands from original f32 inputs
//      -> exact top-32 (idx tiebreak) -> decode.
//
// ws: Bhi 32M | Ahi 8M | cand 1M | pre 32M | list 16M | cnt 16K
//     (total 93,339,648 <= proven 101.7M)

typedef __bf16 bf16x8 __attribute__((ext_vector_type(8)));
typedef float f32x4 __attribute__((ext_vector_type(4)));

#define M_TOK 4096
#define N_CON 16384
#define K_DM  1024
#define NCAND 40
#define LCAP  1024

__device__ __forceinline__ float b2f(unsigned short h) {
  union { unsigned u; float f; } x; x.u = ((unsigned)h) << 16; return x.f;
}
__device__ __forceinline__ unsigned short f2b(float f) {
  union { float f; unsigned u; } x; x.f = f;
  unsigned r = (x.u + 0x7fffu + ((x.u >> 16) & 1u)) >> 16;
  return (unsigned short)r;
}
// monotone 16-bit key for bf16 bits: larger value -> larger key
__device__ __forceinline__ unsigned okey16(unsigned short h) {
  return (h & 0x8000u) ? ((~(unsigned)h) & 0xFFFFu) : ((unsigned)h | 0x8000u);
}
// async global->LDS, 16B per lane; lds base must be wave-uniform
__device__ __forceinline__ void cp16(const void* g, void* l) {
  __builtin_amdgcn_global_load_lds(
      (const __attribute__((address_space(1))) unsigned*)g,
      (__attribute__((address_space(3))) unsigned*)l, 16, 0, 0);
}

// --------------------------------------------------------------- SPLIT ----
__global__ __launch_bounds__(256) void split_kernel(
    const float* __restrict__ A, const float* __restrict__ B,
    unsigned short* __restrict__ Ahi, unsigned short* __restrict__ Bhi,
    int* __restrict__ cnt) {
  const size_t NB4 = (size_t)N_CON * K_DM / 4;  // 4,194,304
  const size_t NA4 = (size_t)M_TOK * K_DM / 4;  // 1,048,576
  size_t i = (size_t)blockIdx.x * 256 + threadIdx.x;
  const float* src; unsigned short* dh; size_t j;
  if (i < NB4) { src = B; dh = Bhi; j = i; }
  else if (i < NB4 + NA4) { src = A; dh = Ahi; j = i - NB4; }
  else {
    const size_t j2 = i - (NB4 + NA4);
    if (cnt && j2 < (size_t)M_TOK) cnt[j2] = 0;
    return;
  }
  const float4 v = *(const float4*)(src + j * 4);
  ushort4 h;
  h.x = f2b(v.x); h.y = f2b(v.y); h.z = f2b(v.z); h.w = f2b(v.w);
  *(ushort4*)(dh + j * 4) = h;
}

// ----------------------------------------------------- GEMM (bf16 MFMA) ----
// 128x128 tile, BK=32, 256 thr (2x2 waves of 64x64).  Staging: async
// global_load_lds dwordx4; tiles UNPADDED [128][32] bf16 (64 B rows) because
// the LDS dest is wave-uniform base + lane*16.  Epilogue: +bias, bf16,
// LDS-staged coalesced store (stride 132) + candidate append (v >= 2.0).
__global__ __launch_bounds__(256) void gemm_bf16(
    const unsigned short* __restrict__ Ahi, const unsigned short* __restrict__ Bhi,
    const float* __restrict__ bias, unsigned short* __restrict__ pre, int m_bits,
    int tok0, unsigned* __restrict__ list, int* __restrict__ cnt) {
  __shared__ __align__(16) char smem[33792];  // >= 2*8192 tiles / 128*132*2 stage
  __bf16* sA = (__bf16*)smem;                  // [128][32]
  __bf16* sB = (__bf16*)(smem + 8192);         // [128][32]

  const int m_mask = (1 << m_bits) - 1;
  const int tile_m = (blockIdx.x & m_mask) << 7;
  const int tile_n = (int)(blockIdx.x >> m_bits) << 7;
  const int tid = threadIdx.x;
  const int wv = tid >> 6, lane = tid & 63;
  const int wm = (wv & 1) << 6, wn = (wv >> 1) << 6;
  const int lm = lane & 15, quad = lane >> 4;
  // staging geometry: segment = 1024 B = 16 rows; wave wv covers segs 2wv,2wv+1
  const int seg0 = wv * 2;
  const int srow = lane >> 2;            // 0..15 within segment
  const int skel = (lane & 3) << 3;      // k element offset 0,8,16,24

  f32x4 acc[4][4] = {};
  for (int k0 = 0; k0 < K_DM; k0 += 32) {
#pragma unroll
    for (int s = 0; s < 2; ++s) {
      const int seg = seg0 + s;
      const int row = (seg << 4) + srow;
      cp16(Ahi + (size_t)(tile_m + row) * K_DM + k0 + skel,
           (char*)sA + (seg << 10));
      cp16(Bhi + (size_t)(tile_n + row) * K_DM + k0 + skel,
           (char*)sB + (seg << 10));
    }
    __syncthreads();  // drains vmcnt -> tiles complete

    bf16x8 af[4], bfr[4];
#pragma unroll
    for (int mi = 0; mi < 4; ++mi)
      af[mi] = *(const bf16x8*)&sA[(wm + mi * 16 + lm) * 32 + quad * 8];
#pragma unroll
    for (int ni = 0; ni < 4; ++ni)
      bfr[ni] = *(const bf16x8*)&sB[(wn + ni * 16 + lm) * 32 + quad * 8];
#pragma unroll
    for (int mi = 0; mi < 4; ++mi)
#pragma unroll
      for (int ni = 0; ni < 4; ++ni)
        acc[mi][ni] = __builtin_amdgcn_mfma_f32_16x16x32_bf16(
            af[mi], bfr[ni], acc[mi][ni], 0, 0, 0);
    __syncthreads();  // all ds_reads done before next overwrite
  }

  float bcol[4];
#pragma unroll
  for (int ni = 0; ni < 4; ++ni) bcol[ni] = bias[tile_n + wn + ni * 16 + lm];
  unsigned short* st = (unsigned short*)smem;  // 128 x 132 shorts = 33792 B
#pragma unroll
  for (int mi = 0; mi < 4; ++mi)
#pragma unroll
    for (int ni = 0; ni < 4; ++ni) {
      const int col = wn + ni * 16 + lm;
#pragma unroll
      for (int r = 0; r < 4; ++r) {
        const float v = acc[mi][ni][r] + bcol[ni];
        const unsigned short h = f2b(v);
        st[(wm + mi * 16 + quad * 4 + r) * 132 + col] = h;
        // candidate append: bf16 value >= 2.0 (positive), okey = h | 0x8000
        if (list && h >= 0x4000u && h < 0x8000u) {
          const int tokg = tok0 + tile_m + wm + mi * 16 + quad * 4 + r;
          const unsigned pk =
              ((((unsigned)h) | 0x8000u) << 14) | (unsigned)(tile_n + col);
          const int pos = atomicAdd(cnt + tokg, 1);
          if (pos < LCAP) list[((size_t)tokg << 10) + pos] = pk;
        }
      }
    }
  __syncthreads();
  const int row = tid >> 1, half = (tid & 1) << 6;
#pragma unroll
  for (int j = 0; j < 8; ++j) {
    *(uint4*)(pre + (size_t)(tile_m + row) * N_CON + tile_n + half + j * 8) =
        *(const uint4*)&st[row * 132 + half + j * 8];
  }
}

// ---------------------------------------------------------- CANDIDATES ----
// Fast path: per-token list of packed (okey16<<14)|idx (all bf16 values
// >= 2.0, written by gemm epilogue).  If 40 <= n <= LCAP the global top-40
// is a subset of the list; rank-select by packed u32 (unique: idx unique)
// gives deterministic top-NCAND with key-then-idx ordering.
// Fallback (n < 40 or overflow): original 2x8-bit radix on the pre row.
__global__ __launch_bounds__(256) void cand_kernel(
    const unsigned short* __restrict__ pre, int* __restrict__ cand, int tok0,
    const unsigned* __restrict__ list, const int* __restrict__ cntp) {
  const int tl = blockIdx.x;
  const int tg = tok0 + tl;
  const unsigned short* row = pre + (size_t)tl * N_CON;
  __shared__ int hist[256];
  __shared__ int scan[256];
  __shared__ int sel_b, sel_above;
  __shared__ int cnt_gt, cnt_eq;
  __shared__ unsigned sL[LCAP];
  const int tid = threadIdx.x;

  int n = -1;
  if (list) n = cntp[tg];
  if (n >= NCAND && n <= LCAP) {
    // ---- fast path: rank-select over the list ----
    for (int i = tid; i < n; i += 256) sL[i] = list[((size_t)tg << 10) + i];
    __syncthreads();
    unsigned mine[4] = {0u, 0u, 0u, 0u};  // 0 sentinel -> rank >= n >= NCAND
#pragma unroll
    for (int q = 0; q < 4; ++q) {
      const int i = tid + (q << 8);
      if (i < n) mine[q] = sL[i];
    }
    int rk0 = 0, rk1 = 0, rk2 = 0, rk3 = 0;
    for (int j = 0; j < n; ++j) {
      const unsigned x = sL[j];  // broadcast read, conflict-free
      rk0 += (x > mine[0]); rk1 += (x > mine[1]);
      rk2 += (x > mine[2]); rk3 += (x > mine[3]);
    }
    int rk[4] = {rk0, rk1, rk2, rk3};
#pragma unroll
    for (int q = 0; q < 4; ++q) {
      const int i = tid + (q << 8);
      if (i < n && rk[q] < NCAND)
        cand[tg * NCAND + rk[q]] = (int)(mine[q] & 0x3FFFu);
    }
    return;
  }

  // ---- fallback: original radix path over pre row ----
  hist[tid] = 0;
  __syncthreads();
  int c_bf = 0;
  for (int i = 0; i < 8; ++i) {
    const uint4 w = *(const uint4*)(row + (size_t)((i << 8) + tid) * 8);
    const unsigned short* hh = (const unsigned short*)&w;
#pragma unroll
    for (int j = 0; j < 8; ++j) {
      const unsigned hb = okey16(hh[j]) >> 8;
      if (hb >= 0xC0u) atomicAdd(&hist[hb], 1);
      else if (hb == 0xBFu) ++c_bf;
    }
  }
  if (c_bf) atomicAdd(&hist[0xBF], c_bf);
  __syncthreads();

  int need = NCAND;
  unsigned prefix = 0u;
  for (int pass = 0; pass < 2; ++pass) {
    scan[tid] = hist[tid];
    __syncthreads();
    for (int off = 1; off < 256; off <<= 1) {  // inclusive suffix sum
      const int v2 = (tid + off < 256) ? scan[tid + off] : 0;
      __syncthreads();
      scan[tid] += v2;
      __syncthreads();
    }
    const int S = scan[tid];
    const int Sn = (tid < 255) ? scan[tid + 1] : 0;
    if (S >= need && Sn < need) { sel_b = tid; sel_above = Sn; }
    __syncthreads();
    need -= sel_above;
    if (pass == 0) {
      prefix = ((unsigned)sel_b) << 8;
      __syncthreads();
      hist[tid] = 0;
      __syncthreads();
      for (int i = 0; i < 8; ++i) {
        const uint4 w = *(const uint4*)(row + (size_t)((i << 8) + tid) * 8);
        const unsigned short* hh = (const unsigned short*)&w;
#pragma unroll
        for (int j = 0; j < 8; ++j) {
          const unsigned key = okey16(hh[j]);
          if ((key >> 8) == (prefix >> 8)) atomicAdd(&hist[key & 255u], 1);
        }
      }
      __syncthreads();
    } else {
      prefix |= (unsigned)sel_b;
    }
  }
  const unsigned T = prefix;
  if (tid == 0) { cnt_gt = 0; cnt_eq = 0; }
  __syncthreads();
  const int base_eq = NCAND - need;
  for (int i = 0; i < 8; ++i) {
    const int c0 = ((i << 8) + tid) * 8;
    const uint4 w = *(const uint4*)(row + c0);
    const unsigned short* hh = (const unsigned short*)&w;
#pragma unroll
    for (int j = 0; j < 8; ++j) {
      const unsigned key = okey16(hh[j]);
      if (key > T) {
        const int p = atomicAdd(&cnt_gt, 1);
        cand[tg * NCAND + p] = c0 + j;
      } else if (key == T) {
        const int p = atomicAdd(&cnt_eq, 1);
        if (p < need) cand[tg * NCAND + base_eq + p] = c0 + j;
      }
    }
  }
}

// ----------------------------------------------------------- TRANSPOSE ----
__global__ __launch_bounds__(256) void transpose_kernel(
    const float* __restrict__ W, unsigned short* __restrict__ WT) {
  __shared__ __align__(16) unsigned short tile[64][72];
  const int c0 = blockIdx.x << 6;
  const int d0 = blockIdx.y << 6;
  const int tid = threadIdx.x;
  const int r = tid >> 3;
  const int o8 = (tid & 7) << 3;
#pragma unroll
  for (int it = 0; it < 2; ++it) {
    const int d = r + it * 32;
    const float4 v0 = *(const float4*)(W + (size_t)(d0 + d) * N_CON + c0 + o8);
    const float4 v1 = *(const float4*)(W + (size_t)(d0 + d) * N_CON + c0 + o8 + 4);
    tile[d][o8 + 0] = f2b(v0.x); tile[d][o8 + 1] = f2b(v0.y);
    tile[d][o8 + 2] = f2b(v0.z); tile[d][o8 + 3] = f2b(v0.w);
    tile[d][o8 + 4] = f2b(v1.x); tile[d][o8 + 5] = f2b(v1.y);
    tile[d][o8 + 6] = f2b(v1.z); tile[d][o8 + 7] = f2b(v1.w);
  }
  __syncthreads();
#pragma unroll
  for (int it = 0; it < 2; ++it) {
    const int c = r + it * 32;
    union { unsigned short u[8]; uint4 q; } tmp;
#pragma unroll
    for (int j = 0; j < 8; ++j) tmp.u[j] = tile[o8 + j][c];
    *(uint4*)(WT + (size_t)(c0 + c) * K_DM + d0 + o8) = tmp.q;
  }
}

// ------------------------------------------------------ REFINE + DECODE ----
// 4 threads per candidate (NCAND*4 = 160 active), exact f64 dots from the
// original f32 inputs, exact top-32 with index tiebreak, then decode.
__global__ __launch_bounds__(256) void refine_decode(
    const float* __restrict__ act, const float* __restrict__ Wenc,
    const float* __restrict__ bias, const int* __restrict__ cand,
    const unsigned short* __restrict__ WT, float* __restrict__ out) {
  const int t = blockIdx.x;
  __shared__ __align__(16) float sact[K_DM];
  __shared__ double vals[NCAND];
  __shared__ int sidx[NCAND];
  __shared__ float sv[32];
  __shared__ int si[32];
  const int tid = threadIdx.x;

  *(float4*)&sact[tid * 4] = *(const float4*)(act + (size_t)t * K_DM + tid * 4);
  if (tid < NCAND) sidx[tid] = cand[t * NCAND + tid];
  __syncthreads();

  if (tid < NCAND * 4) {
    const int g = tid >> 2, i4 = (tid & 3) << 2;
    const int c = sidx[g];
    const float* wrow = Wenc + (size_t)c * K_DM;
    double s[8] = {};
    for (int q = 0; q < 64; q += 8) {
#pragma unroll
      for (int p = 0; p < 8; ++p) {
        const int e = ((q + p) << 4) + i4;
        const float4 w = *(const float4*)(wrow + e);
        const float4 a = *(const float4*)&sact[e];
        s[p] += (double)a.x * (double)w.x + (double)a.y * (double)w.y +
                (double)a.z * (double)w.z + (double)a.w * (double)w.w;
      }
    }
    double sr = ((s[0] + s[1]) + (s[2] + s[3])) + ((s[4] + s[5]) + (s[6] + s[7]));
    sr += __shfl_xor(sr, 1);
    sr += __shfl_xor(sr, 2);
    if ((tid & 3) == 0) vals[g] = sr + (double)bias[c];
  }
  __syncthreads();

  if (tid < NCAND) {
    const double v = vals[tid];
    const int ci = sidx[tid];
    int rank = 0;
    for (int j = 0; j < NCAND; ++j) {
      const double vj = vals[j];
      if (vj > v || (vj == v && sidx[j] < ci)) ++rank;
    }
    if (rank < 32) { sv[rank] = (float)v; si[rank] = ci; }
  }
  __syncthreads();

  const int d4 = tid << 2;
  float a0 = 0.f, a1 = 0.f, a2 = 0.f, a3 = 0.f;
#pragma unroll
  for (int j = 0; j < 32; ++j) {
    const float v = sv[j];
    const ushort4 w = *(const ushort4*)(WT + (size_t)si[j] * K_DM + d4);
    a0 += v * b2f(w.x); a1 += v * b2f(w.y);
    a2 += v * b2f(w.z); a3 += v * b2f(w.w);
  }
  float4 o; o.x = a0; o.y = a1; o.z = a2; o.w = a3;
  *(float4*)(out + (size_t)t * K_DM + d4) = o;
}

extern "C" void kernel_launch(void* const* d_in, const int* in_sizes, int n_in,
                              void* d_out, int out_size, void* d_ws, size_t ws_size,
                              hipStream_t stream) {
  const float* act  = (const float*)d_in[0];  // [4096][1024]
  const float* Wenc = (const float*)d_in[1];  // [16384][1024]
  const float* bias = (const float*)d_in[2];  // [16384]
  const float* Wemb = (const float*)d_in[3];  // [1024][16384]
  (void)in_sizes; (void)n_in; (void)out_size;
  float* out = (float*)d_out;

  char* ws = (char*)d_ws;
  unsigned short* Bhi = (unsigned short*)ws;                  // 33,554,432
  unsigned short* Ahi = (unsigned short*)(ws + 33554432ull);  //  8,388,608
  int* cand           = (int*)(ws + 41943040ull);             //  1,048,576 (need 655,360)
  const size_t PRE_OFF = 42991616ull;
  unsigned short* pre = (unsigned short*)(ws + PRE_OFF);
  unsigned short* WT  = (unsigned short*)ws;  // aliases Bhi after last gemm

  // candidate lists beyond max pre: list 16 MB + cnt 16 KB
  const size_t LIST_OFF = 76546048ull;               // = PRE_OFF + 32M
  const size_t CNT_OFF  = LIST_OFF + 16777216ull;    // 93,323,264
  unsigned* list = nullptr; int* cntp = nullptr;
  if (ws_size >= CNT_OFF + 16384ull) {
    list = (unsigned*)(ws + LIST_OFF);
    cntp = (int*)(ws + CNT_OFF);
  }

  int chunk = 256, m_bits = 1;
  if (ws_size >= PRE_OFF + 33554432ull) { chunk = 1024; m_bits = 3; }
  else if (ws_size >= PRE_OFF + 16777216ull) { chunk = 512; m_bits = 2; }

  // 20480 blocks of data + 16 blocks zeroing the 4096 counters
  split_kernel<<<dim3(20496), dim3(256), 0, stream>>>(act, Wenc, Ahi, Bhi, cntp);

  for (int tok0 = 0; tok0 < M_TOK; tok0 += chunk) {
    const int grid = (chunk / 128) * (N_CON / 128);
    gemm_bf16<<<dim3(grid), dim3(256), 0, stream>>>(
        Ahi + (size_t)tok0 * K_DM, Bhi, bias, pre, m_bits, tok0, list, cntp);
    cand_kernel<<<dim3(chunk), dim3(256), 0, stream>>>(pre, cand, tok0, list, cntp);
  }

  transpose_kernel<<<dim3(N_CON / 64, K_DM / 64), dim3(256), 0, stream>>>(Wemb, WT);
  refine_decode<<<dim3(M_TOK), dim3(256), 0, stream>>>(act, Wenc, bias, cand, WT, out);
}

// Round 2
// 687.178 us; speedup vs baseline: 2.1423x; 2.1423x over previous
//
#include <hip/hip_runtime.h>

// SparseEncoder: 4096 tokens, d_model=1024, d_concepts=16384, k=32. f32 in/out.
//
// R8 pipeline:
//   1) split:  act,Wenc f32 -> bf16
//   2) gemm_bf16 (per 1024-token chunk): pre_bf16 = bf16(A@B^T + bias);
//      m97-style global_load_lds width=16 staging (unpadded 128x32 tiles).
//      (R6 form, byte-identical: R7's global-atomic append contended 128
//      blocks x 8 XCDs on 64 cache lines -> 3x gemm slowdown. Reverted.)
//   3) cand: FAST PATH = single pass over the pre row; values >= 2.0
//      (~373/token) appended to an LDS list via LDS atomics, then exact
//      rank-select over packed (okey16<<14)|idx -> top-40.  Sound gate:
//      n>=40 entries >= 2.0  =>  global top-40 is a subset of the list.
//      Fallback (n<40 or n>1024): original 2x8-bit radix (3-pass).
//   4) transpose: W_emb f32 -> WT bf16 (aliases Bhi after last gemm)
//   5) refine_decode: exact f64 dots for 40 cands from original f32 inputs
//      -> exact top-32 (idx tiebreak) -> decode.
//
// ws: Bhi 32M | Ahi 8M | cand 1M | pre 32M  (total 76,546,048 <= proven 101.7M)

typedef __bf16 bf16x8 __attribute__((ext_vector_type(8)));
typedef float f32x4 __attribute__((ext_vector_type(4)));

#define M_TOK 4096
#define N_CON 16384
#define K_DM  1024
#define NCAND 40
#define LCAP  1024

__device__ __forceinline__ float b2f(unsigned short h) {
  union { unsigned u; float f; } x; x.u = ((unsigned)h) << 16; return x.f;
}
__device__ __forceinline__ unsigned short f2b(float f) {
  union { float f; unsigned u; } x; x.f = f;
  unsigned r = (x.u + 0x7fffu + ((x.u >> 16) & 1u)) >> 16;
  return (unsigned short)r;
}
// monotone 16-bit key for bf16 bits: larger value -> larger key
__device__ __forceinline__ unsigned okey16(unsigned short h) {
  return (h & 0x8000u) ? ((~(unsigned)h) & 0xFFFFu) : ((unsigned)h | 0x8000u);
}
// async global->LDS, 16B per lane; lds base must be wave-uniform
__device__ __forceinline__ void cp16(const void* g, void* l) {
  __builtin_amdgcn_global_load_lds(
      (const __attribute__((address_space(1))) unsigned*)g,
      (__attribute__((address_space(3))) unsigned*)l, 16, 0, 0);
}

// --------------------------------------------------------------- SPLIT ----
__global__ __launch_bounds__(256) void split_kernel(
    const float* __restrict__ A, const float* __restrict__ B,
    unsigned short* __restrict__ Ahi, unsigned short* __restrict__ Bhi) {
  const size_t NB4 = (size_t)N_CON * K_DM / 4;  // 4,194,304
  const size_t NA4 = (size_t)M_TOK * K_DM / 4;  // 1,048,576
  size_t i = (size_t)blockIdx.x * 256 + threadIdx.x;
  const float* src; unsigned short* dh; size_t j;
  if (i < NB4) { src = B; dh = Bhi; j = i; }
  else if (i < NB4 + NA4) { src = A; dh = Ahi; j = i - NB4; }
  else return;
  const float4 v = *(const float4*)(src + j * 4);
  ushort4 h;
  h.x = f2b(v.x); h.y = f2b(v.y); h.z = f2b(v.z); h.w = f2b(v.w);
  *(ushort4*)(dh + j * 4) = h;
}

// ----------------------------------------------------- GEMM (bf16 MFMA) ----
// 128x128 tile, BK=32, 256 thr (2x2 waves of 64x64).  Staging: async
// global_load_lds dwordx4; tiles UNPADDED [128][32] bf16 (64 B rows) because
// the LDS dest is wave-uniform base + lane*16.  Epilogue: +bias, bf16,
// LDS-staged coalesced store (stride 132).
__global__ __launch_bounds__(256) void gemm_bf16(
    const unsigned short* __restrict__ Ahi, const unsigned short* __restrict__ Bhi,
    const float* __restrict__ bias, unsigned short* __restrict__ pre, int m_bits) {
  __shared__ __align__(16) char smem[33792];  // >= 2*8192 tiles / 128*132*2 stage
  __bf16* sA = (__bf16*)smem;                  // [128][32]
  __bf16* sB = (__bf16*)(smem + 8192);         // [128][32]

  const int m_mask = (1 << m_bits) - 1;
  const int tile_m = (blockIdx.x & m_mask) << 7;
  const int tile_n = (int)(blockIdx.x >> m_bits) << 7;
  const int tid = threadIdx.x;
  const int wv = tid >> 6, lane = tid & 63;
  const int wm = (wv & 1) << 6, wn = (wv >> 1) << 6;
  const int lm = lane & 15, quad = lane >> 4;
  // staging geometry: segment = 1024 B = 16 rows; wave wv covers segs 2wv,2wv+1
  const int seg0 = wv * 2;
  const int srow = lane >> 2;            // 0..15 within segment
  const int skel = (lane & 3) << 3;      // k element offset 0,8,16,24

  f32x4 acc[4][4] = {};
  for (int k0 = 0; k0 < K_DM; k0 += 32) {
#pragma unroll
    for (int s = 0; s < 2; ++s) {
      const int seg = seg0 + s;
      const int row = (seg << 4) + srow;
      cp16(Ahi + (size_t)(tile_m + row) * K_DM + k0 + skel,
           (char*)sA + (seg << 10));
      cp16(Bhi + (size_t)(tile_n + row) * K_DM + k0 + skel,
           (char*)sB + (seg << 10));
    }
    __syncthreads();  // drains vmcnt -> tiles complete

    bf16x8 af[4], bfr[4];
#pragma unroll
    for (int mi = 0; mi < 4; ++mi)
      af[mi] = *(const bf16x8*)&sA[(wm + mi * 16 + lm) * 32 + quad * 8];
#pragma unroll
    for (int ni = 0; ni < 4; ++ni)
      bfr[ni] = *(const bf16x8*)&sB[(wn + ni * 16 + lm) * 32 + quad * 8];
#pragma unroll
    for (int mi = 0; mi < 4; ++mi)
#pragma unroll
      for (int ni = 0; ni < 4; ++ni)
        acc[mi][ni] = __builtin_amdgcn_mfma_f32_16x16x32_bf16(
            af[mi], bfr[ni], acc[mi][ni], 0, 0, 0);
    __syncthreads();  // all ds_reads done before next overwrite
  }

  float bcol[4];
#pragma unroll
  for (int ni = 0; ni < 4; ++ni) bcol[ni] = bias[tile_n + wn + ni * 16 + lm];
  unsigned short* st = (unsigned short*)smem;  // 128 x 132 shorts = 33792 B
#pragma unroll
  for (int mi = 0; mi < 4; ++mi)
#pragma unroll
    for (int ni = 0; ni < 4; ++ni) {
      const int col = wn + ni * 16 + lm;
#pragma unroll
      for (int r = 0; r < 4; ++r)
        st[(wm + mi * 16 + quad * 4 + r) * 132 + col] = f2b(acc[mi][ni][r] + bcol[ni]);
    }
  __syncthreads();
  const int row = tid >> 1, half = (tid & 1) << 6;
#pragma unroll
  for (int j = 0; j < 8; ++j) {
    *(uint4*)(pre + (size_t)(tile_m + row) * N_CON + tile_n + half + j * 8) =
        *(const uint4*)&st[row * 132 + half + j * 8];
  }
}

// ---------------------------------------------------------- CANDIDATES ----
// FAST PATH (single pass): collect all values >= 2.0 (bf16 bits in
// [0x4000,0x8000)) into an LDS list via LDS atomics (~373/token), then exact
// rank-select by packed (okey16<<14)|idx (unique keys -> unique ranks).
// If n >= NCAND, the rank-NCAND value is >= 2.0, so the global top-NCAND is
// a subset of the list.  Fallback (n < NCAND or n > LCAP): original 2x8-bit
// radix over the pre row with the >= 0.5 floor.
__global__ __launch_bounds__(256) void cand_kernel(
    const unsigned short* __restrict__ pre, int* __restrict__ cand, int tok0) {
  const int tl = blockIdx.x;
  const int tg = tok0 + tl;
  const unsigned short* row = pre + (size_t)tl * N_CON;
  __shared__ unsigned sL[LCAP];
  __shared__ int lcnt;
  __shared__ int hist[256];
  __shared__ int scan[256];
  __shared__ int sel_b, sel_above;
  __shared__ int cnt_gt, cnt_eq;
  const int tid = threadIdx.x;

  if (tid == 0) lcnt = 0;
  __syncthreads();
  for (int i = 0; i < 8; ++i) {
    const int c0 = ((i << 8) + tid) * 8;
    const uint4 w = *(const uint4*)(row + c0);
    const unsigned short* hh = (const unsigned short*)&w;
#pragma unroll
    for (int j = 0; j < 8; ++j) {
      const unsigned short h = hh[j];
      if (h >= 0x4000u && h < 0x8000u) {  // v >= 2.0, positive finite
        const int pos = atomicAdd(&lcnt, 1);
        if (pos < LCAP)
          sL[pos] = ((((unsigned)h) | 0x8000u) << 14) | (unsigned)(c0 + j);
      }
    }
  }
  __syncthreads();
  const int n = lcnt;
  if (n >= NCAND && n <= LCAP) {
    unsigned m0 = 0u, m1 = 0u, m2 = 0u, m3 = 0u;  // 0 sentinel -> rank >= n
    if (tid < n) m0 = sL[tid];
    if (tid + 256 < n) m1 = sL[tid + 256];
    if (tid + 512 < n) m2 = sL[tid + 512];
    if (tid + 768 < n) m3 = sL[tid + 768];
    int rk0 = 0, rk1 = 0, rk2 = 0, rk3 = 0;
    for (int j = 0; j < n; ++j) {
      const unsigned x = sL[j];  // broadcast read, conflict-free
      rk0 += (x > m0); rk1 += (x > m1); rk2 += (x > m2); rk3 += (x > m3);
    }
    if (tid < n && rk0 < NCAND) cand[tg * NCAND + rk0] = (int)(m0 & 0x3FFFu);
    if (tid + 256 < n && rk1 < NCAND) cand[tg * NCAND + rk1] = (int)(m1 & 0x3FFFu);
    if (tid + 512 < n && rk2 < NCAND) cand[tg * NCAND + rk2] = (int)(m2 & 0x3FFFu);
    if (tid + 768 < n && rk3 < NCAND) cand[tg * NCAND + rk3] = (int)(m3 & 0x3FFFu);
    return;
  }

  // ---- fallback: original radix path over pre row ----
  hist[tid] = 0;
  __syncthreads();
  int c_bf = 0;
  for (int i = 0; i < 8; ++i) {
    const uint4 w = *(const uint4*)(row + (size_t)((i << 8) + tid) * 8);
    const unsigned short* hh = (const unsigned short*)&w;
#pragma unroll
    for (int j = 0; j < 8; ++j) {
      const unsigned hb = okey16(hh[j]) >> 8;
      if (hb >= 0xC0u) atomicAdd(&hist[hb], 1);
      else if (hb == 0xBFu) ++c_bf;
    }
  }
  if (c_bf) atomicAdd(&hist[0xBF], c_bf);
  __syncthreads();

  int need = NCAND;
  unsigned prefix = 0u;
  for (int pass = 0; pass < 2; ++pass) {
    scan[tid] = hist[tid];
    __syncthreads();
    for (int off = 1; off < 256; off <<= 1) {  // inclusive suffix sum
      const int v2 = (tid + off < 256) ? scan[tid + off] : 0;
      __syncthreads();
      scan[tid] += v2;
      __syncthreads();
    }
    const int S = scan[tid];
    const int Sn = (tid < 255) ? scan[tid + 1] : 0;
    if (S >= need && Sn < need) { sel_b = tid; sel_above = Sn; }
    __syncthreads();
    need -= sel_above;
    if (pass == 0) {
      prefix = ((unsigned)sel_b) << 8;
      __syncthreads();
      hist[tid] = 0;
      __syncthreads();
      for (int i = 0; i < 8; ++i) {
        const uint4 w = *(const uint4*)(row + (size_t)((i << 8) + tid) * 8);
        const unsigned short* hh = (const unsigned short*)&w;
#pragma unroll
        for (int j = 0; j < 8; ++j) {
          const unsigned key = okey16(hh[j]);
          if ((key >> 8) == (prefix >> 8)) atomicAdd(&hist[key & 255u], 1);
        }
      }
      __syncthreads();
    } else {
      prefix |= (unsigned)sel_b;
    }
  }
  const unsigned T = prefix;
  if (tid == 0) { cnt_gt = 0; cnt_eq = 0; }
  __syncthreads();
  const int base_eq = NCAND - need;
  for (int i = 0; i < 8; ++i) {
    const int c0 = ((i << 8) + tid) * 8;
    const uint4 w = *(const uint4*)(row + c0);
    const unsigned short* hh = (const unsigned short*)&w;
#pragma unroll
    for (int j = 0; j < 8; ++j) {
      const unsigned key = okey16(hh[j]);
      if (key > T) {
        const int p = atomicAdd(&cnt_gt, 1);
        cand[tg * NCAND + p] = c0 + j;
      } else if (key == T) {
        const int p = atomicAdd(&cnt_eq, 1);
        if (p < need) cand[tg * NCAND + base_eq + p] = c0 + j;
      }
    }
  }
}

// ----------------------------------------------------------- TRANSPOSE ----
__global__ __launch_bounds__(256) void transpose_kernel(
    const float* __restrict__ W, unsigned short* __restrict__ WT) {
  __shared__ __align__(16) unsigned short tile[64][72];
  const int c0 = blockIdx.x << 6;
  const int d0 = blockIdx.y << 6;
  const int tid = threadIdx.x;
  const int r = tid >> 3;
  const int o8 = (tid & 7) << 3;
#pragma unroll
  for (int it = 0; it < 2; ++it) {
    const int d = r + it * 32;
    const float4 v0 = *(const float4*)(W + (size_t)(d0 + d) * N_CON + c0 + o8);
    const float4 v1 = *(const float4*)(W + (size_t)(d0 + d) * N_CON + c0 + o8 + 4);
    tile[d][o8 + 0] = f2b(v0.x); tile[d][o8 + 1] = f2b(v0.y);
    tile[d][o8 + 2] = f2b(v0.z); tile[d][o8 + 3] = f2b(v0.w);
    tile[d][o8 + 4] = f2b(v1.x); tile[d][o8 + 5] = f2b(v1.y);
    tile[d][o8 + 6] = f2b(v1.z); tile[d][o8 + 7] = f2b(v1.w);
  }
  __syncthreads();
#pragma unroll
  for (int it = 0; it < 2; ++it) {
    const int c = r + it * 32;
    union { unsigned short u[8]; uint4 q; } tmp;
#pragma unroll
    for (int j = 0; j < 8; ++j) tmp.u[j] = tile[o8 + j][c];
    *(uint4*)(WT + (size_t)(c0 + c) * K_DM + d0 + o8) = tmp.q;
  }
}

// ------------------------------------------------------ REFINE + DECODE ----
// 4 threads per candidate (NCAND*4 = 160 active), exact f64 dots from the
// original f32 inputs, exact top-32 with index tiebreak, then decode.
__global__ __launch_bounds__(256) void refine_decode(
    const float* __restrict__ act, const float* __restrict__ Wenc,
    const float* __restrict__ bias, const int* __restrict__ cand,
    const unsigned short* __restrict__ WT, float* __restrict__ out) {
  const int t = blockIdx.x;
  __shared__ __align__(16) float sact[K_DM];
  __shared__ double vals[NCAND];
  __shared__ int sidx[NCAND];
  __shared__ float sv[32];
  __shared__ int si[32];
  const int tid = threadIdx.x;

  *(float4*)&sact[tid * 4] = *(const float4*)(act + (size_t)t * K_DM + tid * 4);
  if (tid < NCAND) sidx[tid] = cand[t * NCAND + tid];
  __syncthreads();

  if (tid < NCAND * 4) {
    const int g = tid >> 2, i4 = (tid & 3) << 2;
    const int c = sidx[g];
    const float* wrow = Wenc + (size_t)c * K_DM;
    double s[8] = {};
    for (int q = 0; q < 64; q += 8) {
#pragma unroll
      for (int p = 0; p < 8; ++p) {
        const int e = ((q + p) << 4) + i4;
        const float4 w = *(const float4*)(wrow + e);
        const float4 a = *(const float4*)&sact[e];
        s[p] += (double)a.x * (double)w.x + (double)a.y * (double)w.y +
                (double)a.z * (double)w.z + (double)a.w * (double)w.w;
      }
    }
    double sr = ((s[0] + s[1]) + (s[2] + s[3])) + ((s[4] + s[5]) + (s[6] + s[7]));
    sr += __shfl_xor(sr, 1);
    sr += __shfl_xor(sr, 2);
    if ((tid & 3) == 0) vals[g] = sr + (double)bias[c];
  }
  __syncthreads();

  if (tid < NCAND) {
    const double v = vals[tid];
    const int ci = sidx[tid];
    int rank = 0;
    for (int j = 0; j < NCAND; ++j) {
      const double vj = vals[j];
      if (vj > v || (vj == v && sidx[j] < ci)) ++rank;
    }
    if (rank < 32) { sv[rank] = (float)v; si[rank] = ci; }
  }
  __syncthreads();

  const int d4 = tid << 2;
  float a0 = 0.f, a1 = 0.f, a2 = 0.f, a3 = 0.f;
#pragma unroll
  for (int j = 0; j < 32; ++j) {
    const float v = sv[j];
    const ushort4 w = *(const ushort4*)(WT + (size_t)si[j] * K_DM + d4);
    a0 += v * b2f(w.x); a1 += v * b2f(w.y);
    a2 += v * b2f(w.z); a3 += v * b2f(w.w);
  }
  float4 o; o.x = a0; o.y = a1; o.z = a2; o.w = a3;
  *(float4*)(out + (size_t)t * K_DM + d4) = o;
}

extern "C" void kernel_launch(void* const* d_in, const int* in_sizes, int n_in,
                              void* d_out, int out_size, void* d_ws, size_t ws_size,
                              hipStream_t stream) {
  const float* act  = (const float*)d_in[0];  // [4096][1024]
  const float* Wenc = (const float*)d_in[1];  // [16384][1024]
  const float* bias = (const float*)d_in[2];  // [16384]
  const float* Wemb = (const float*)d_in[3];  // [1024][16384]
  (void)in_sizes; (void)n_in; (void)out_size;
  float* out = (float*)d_out;

  char* ws = (char*)d_ws;
  unsigned short* Bhi = (unsigned short*)ws;                  // 33,554,432
  unsigned short* Ahi = (unsigned short*)(ws + 33554432ull);  //  8,388,608
  int* cand           = (int*)(ws + 41943040ull);             //  1,048,576 (need 655,360)
  const size_t PRE_OFF = 42991616ull;
  unsigned short* pre = (unsigned short*)(ws + PRE_OFF);
  unsigned short* WT  = (unsigned short*)ws;  // aliases Bhi after last gemm

  int chunk = 256, m_bits = 1;
  if (ws_size >= PRE_OFF + 33554432ull) { chunk = 1024; m_bits = 3; }
  else if (ws_size >= PRE_OFF + 16777216ull) { chunk = 512; m_bits = 2; }

  split_kernel<<<dim3(20480), dim3(256), 0, stream>>>(act, Wenc, Ahi, Bhi);

  for (int tok0 = 0; tok0 < M_TOK; tok0 += chunk) {
    const int grid = (chunk / 128) * (N_CON / 128);
    gemm_bf16<<<dim3(grid), dim3(256), 0, stream>>>(
        Ahi + (size_t)tok0 * K_DM, Bhi, bias, pre, m_bits);
    cand_kernel<<<dim3(chunk), dim3(256), 0, stream>>>(pre, cand, tok0);
  }

  transpose_kernel<<<dim3(N_CON / 64, K_DM / 64), dim3(256), 0, stream>>>(Wemb, WT);
  refine_decode<<<dim3(M_TOK), dim3(256), 0, stream>>>(act, Wenc, bias, cand, WT, out);
}

// Round 3
// 653.867 us; speedup vs baseline: 2.2514x; 1.0509x over previous
//
#include <hip/hip_runtime.h>

// SparseEncoder: 4096 tokens, d_model=1024, d_concepts=16384, k=32. f32 in/out.
//
// R9 pipeline:
//   1) split:  act,Wenc f32 -> bf16
//   2) gemm_bf16 (per 1024-token chunk): pre_bf16 = bf16(A@B^T + bias).
//      NEW vs R6: (a) XCD-aware bijective blockIdx swizzle (each XCD gets a
//      contiguous n-panel range -> B slice 4MB stays L2-resident; B fetched
//      from HBM once, not ~4x), (b) double-buffered LDS staging: next K-tile's
//      global_load_lds issued BEFORE current tile's MFMA phase, single
//      __syncthreads per K-step (its implicit vmcnt(0) drain lands after
//      compute -> staging latency hidden).
//   3) cand: single pass, values >= 2.0 -> LDS list via LDS atomics, exact
//      rank-select over packed (okey16<<14)|idx, vectorized 4 keys/iter.
//      Fallback (n<40 or n>1024): original 2x8-bit radix.
//   4) transpose: W_emb f32 -> WT bf16 (aliases Bhi after last gemm)
//   5) refine_decode: exact f64 dots for 40 cands from original f32 inputs
//      -> exact top-32 (idx tiebreak) -> decode.
//
// ws: Bhi 32M | Ahi 8M | cand 1M | pre 32M  (total 76,546,048 <= proven 101.7M)

typedef __bf16 bf16x8 __attribute__((ext_vector_type(8)));
typedef float f32x4 __attribute__((ext_vector_type(4)));

#define M_TOK 4096
#define N_CON 16384
#define K_DM  1024
#define NCAND 40
#define LCAP  1024

__device__ __forceinline__ float b2f(unsigned short h) {
  union { unsigned u; float f; } x; x.u = ((unsigned)h) << 16; return x.f;
}
__device__ __forceinline__ unsigned short f2b(float f) {
  union { float f; unsigned u; } x; x.f = f;
  unsigned r = (x.u + 0x7fffu + ((x.u >> 16) & 1u)) >> 16;
  return (unsigned short)r;
}
// monotone 16-bit key for bf16 bits: larger value -> larger key
__device__ __forceinline__ unsigned okey16(unsigned short h) {
  return (h & 0x8000u) ? ((~(unsigned)h) & 0xFFFFu) : ((unsigned)h | 0x8000u);
}
// async global->LDS, 16B per lane; lds base must be wave-uniform
__device__ __forceinline__ void cp16(const void* g, void* l) {
  __builtin_amdgcn_global_load_lds(
      (const __attribute__((address_space(1))) unsigned*)g,
      (__attribute__((address_space(3))) unsigned*)l, 16, 0, 0);
}

// --------------------------------------------------------------- SPLIT ----
__global__ __launch_bounds__(256) void split_kernel(
    const float* __restrict__ A, const float* __restrict__ B,
    unsigned short* __restrict__ Ahi, unsigned short* __restrict__ Bhi) {
  const size_t NB4 = (size_t)N_CON * K_DM / 4;  // 4,194,304
  const size_t NA4 = (size_t)M_TOK * K_DM / 4;  // 1,048,576
  size_t i = (size_t)blockIdx.x * 256 + threadIdx.x;
  const float* src; unsigned short* dh; size_t j;
  if (i < NB4) { src = B; dh = Bhi; j = i; }
  else if (i < NB4 + NA4) { src = A; dh = Ahi; j = i - NB4; }
  else return;
  const float4 v = *(const float4*)(src + j * 4);
  ushort4 h;
  h.x = f2b(v.x); h.y = f2b(v.y); h.z = f2b(v.z); h.w = f2b(v.w);
  *(ushort4*)(dh + j * 4) = h;
}

// ----------------------------------------------------- GEMM (bf16 MFMA) ----
// 128x128 tile, BK=32, 256 thr (2x2 waves of 64x64).  Double-buffered async
// staging (global_load_lds dwordx4, unpadded [128][32] bf16 tiles); one
// barrier per K-step.  XCD-swizzled blockIdx for B-panel L2 residency.
// Epilogue: +bias, bf16, LDS-staged coalesced store (stride 132).
__global__ __launch_bounds__(256) void gemm_bf16(
    const unsigned short* __restrict__ Ahi, const unsigned short* __restrict__ Bhi,
    const float* __restrict__ bias, unsigned short* __restrict__ pre, int m_bits) {
  __shared__ __align__(16) char smem[33792];  // 2x(A8K+B8K) dbuf / 128*132*2 stage

  // XCD-aware bijective swizzle: hw blocks round-robin XCDs (b&7); give each
  // XCD a contiguous logical chunk so its B n-panels stay in its private L2.
  // Valid because gridDim.x % 8 == 0 for all chunk configs (256/512/1024).
  const int q = (int)gridDim.x >> 3;
  const int b = (int)blockIdx.x;
  const int lb = (b & 7) * q + (b >> 3);

  const int m_mask = (1 << m_bits) - 1;
  const int tile_m = (lb & m_mask) << 7;
  const int tile_n = (lb >> m_bits) << 7;
  const int tid = threadIdx.x;
  const int wv = tid >> 6, lane = tid & 63;
  const int wm = (wv & 1) << 6, wn = (wv >> 1) << 6;
  const int lm = lane & 15, quad = lane >> 4;
  // staging geometry: segment = 1024 B = 16 rows; wave wv covers segs 2wv,2wv+1
  const int seg0 = wv * 2;
  const int srow = lane >> 2;            // 0..15 within segment
  const int skel = (lane & 3) << 3;      // k element offset 0,8,16,24

#define STAGE(buf, k0)                                                     \
  {                                                                        \
    char* base_ = smem + ((buf) << 14);                                    \
    _Pragma("unroll")                                                      \
    for (int s = 0; s < 2; ++s) {                                          \
      const int seg = seg0 + s;                                            \
      const int row = (seg << 4) + srow;                                   \
      cp16(Ahi + (size_t)(tile_m + row) * K_DM + (k0) + skel,              \
           base_ + (seg << 10));                                           \
      cp16(Bhi + (size_t)(tile_n + row) * K_DM + (k0) + skel,              \
           base_ + 8192 + (seg << 10));                                    \
    }                                                                      \
  }

  f32x4 acc[4][4] = {};
  STAGE(0, 0);
  __syncthreads();  // vmcnt(0) drain: buf0 tiles complete
  int cur = 0;
  for (int k0 = 0; k0 < K_DM; k0 += 32) {
    if (k0 + 32 < K_DM) STAGE(cur ^ 1, k0 + 32);  // prefetch next (in flight)

    const __bf16* sA = (const __bf16*)(smem + (cur << 14));
    const __bf16* sB = (const __bf16*)(smem + (cur << 14) + 8192);
    bf16x8 af[4], bfr[4];
#pragma unroll
    for (int mi = 0; mi < 4; ++mi)
      af[mi] = *(const bf16x8*)&sA[(wm + mi * 16 + lm) * 32 + quad * 8];
#pragma unroll
    for (int ni = 0; ni < 4; ++ni)
      bfr[ni] = *(const bf16x8*)&sB[(wn + ni * 16 + lm) * 32 + quad * 8];
#pragma unroll
    for (int mi = 0; mi < 4; ++mi)
#pragma unroll
      for (int ni = 0; ni < 4; ++ni)
        acc[mi][ni] = __builtin_amdgcn_mfma_f32_16x16x32_bf16(
            af[mi], bfr[ni], acc[mi][ni], 0, 0, 0);
    __syncthreads();  // drains vmcnt (next tiles ready) + lgkmcnt (reads done)
    cur ^= 1;
  }
#undef STAGE

  float bcol[4];
#pragma unroll
  for (int ni = 0; ni < 4; ++ni) bcol[ni] = bias[tile_n + wn + ni * 16 + lm];
  unsigned short* st = (unsigned short*)smem;  // 128 x 132 shorts = 33792 B
#pragma unroll
  for (int mi = 0; mi < 4; ++mi)
#pragma unroll
    for (int ni = 0; ni < 4; ++ni) {
      const int col = wn + ni * 16 + lm;
#pragma unroll
      for (int r = 0; r < 4; ++r)
        st[(wm + mi * 16 + quad * 4 + r) * 132 + col] = f2b(acc[mi][ni][r] + bcol[ni]);
    }
  __syncthreads();
  const int row = tid >> 1, half = (tid & 1) << 6;
#pragma unroll
  for (int j = 0; j < 8; ++j) {
    *(uint4*)(pre + (size_t)(tile_m + row) * N_CON + tile_n + half + j * 8) =
        *(const uint4*)&st[row * 132 + half + j * 8];
  }
}

// ---------------------------------------------------------- CANDIDATES ----
// FAST PATH (single pass): collect all values >= 2.0 (bf16 bits in
// [0x4000,0x8000)) into an LDS list via LDS atomics (~373/token), then exact
// rank-select by packed (okey16<<14)|idx (unique keys -> unique ranks),
// vectorized 4 keys per ds_read_b128.  If n >= NCAND, the rank-NCAND value
// is >= 2.0, so the global top-NCAND is a subset of the list.  Fallback
// (n < NCAND or n > LCAP): original 2x8-bit radix with the >= 0.5 floor.
__global__ __launch_bounds__(256) void cand_kernel(
    const unsigned short* __restrict__ pre, int* __restrict__ cand, int tok0) {
  const int tl = blockIdx.x;
  const int tg = tok0 + tl;
  const unsigned short* row = pre + (size_t)tl * N_CON;
  __shared__ __align__(16) unsigned sL[LCAP];
  __shared__ int lcnt;
  __shared__ int hist[256];
  __shared__ int scan[256];
  __shared__ int sel_b, sel_above;
  __shared__ int cnt_gt, cnt_eq;
  const int tid = threadIdx.x;

  if (tid == 0) lcnt = 0;
  __syncthreads();
  for (int i = 0; i < 8; ++i) {
    const int c0 = ((i << 8) + tid) * 8;
    const uint4 w = *(const uint4*)(row + c0);
    const unsigned short* hh = (const unsigned short*)&w;
#pragma unroll
    for (int j = 0; j < 8; ++j) {
      const unsigned short h = hh[j];
      if (h >= 0x4000u && h < 0x8000u) {  // v >= 2.0, positive finite
        const int pos = atomicAdd(&lcnt, 1);
        if (pos < LCAP)
          sL[pos] = ((((unsigned)h) | 0x8000u) << 14) | (unsigned)(c0 + j);
      }
    }
  }
  __syncthreads();
  const int n = lcnt;
  if (n >= NCAND && n <= LCAP) {
    const int n_pad = (n + 3) & ~3;      // <= LCAP always
    if (n + tid < n_pad) sL[n + tid] = 0u;  // zero-pad to multiple of 4
    __syncthreads();
    unsigned m0 = 0u, m1 = 0u, m2 = 0u, m3 = 0u;  // 0 sentinel -> rank >= n
    if (tid < n) m0 = sL[tid];
    if (tid + 256 < n) m1 = sL[tid + 256];
    if (tid + 512 < n) m2 = sL[tid + 512];
    if (tid + 768 < n) m3 = sL[tid + 768];
    int rk0 = 0, rk1 = 0, rk2 = 0, rk3 = 0;
    for (int j = 0; j < n_pad; j += 4) {
      const uint4 x = *(const uint4*)&sL[j];  // broadcast, conflict-free
      rk0 += (x.x > m0) + (x.y > m0) + (x.z > m0) + (x.w > m0);
      rk1 += (x.x > m1) + (x.y > m1) + (x.z > m1) + (x.w > m1);
      rk2 += (x.x > m2) + (x.y > m2) + (x.z > m2) + (x.w > m2);
      rk3 += (x.x > m3) + (x.y > m3) + (x.z > m3) + (x.w > m3);
    }
    if (tid < n && rk0 < NCAND) cand[tg * NCAND + rk0] = (int)(m0 & 0x3FFFu);
    if (tid + 256 < n && rk1 < NCAND) cand[tg * NCAND + rk1] = (int)(m1 & 0x3FFFu);
    if (tid + 512 < n && rk2 < NCAND) cand[tg * NCAND + rk2] = (int)(m2 & 0x3FFFu);
    if (tid + 768 < n && rk3 < NCAND) cand[tg * NCAND + rk3] = (int)(m3 & 0x3FFFu);
    return;
  }

  // ---- fallback: original radix path over pre row ----
  hist[tid] = 0;
  __syncthreads();
  int c_bf = 0;
  for (int i = 0; i < 8; ++i) {
    const uint4 w = *(const uint4*)(row + (size_t)((i << 8) + tid) * 8);
    const unsigned short* hh = (const unsigned short*)&w;
#pragma unroll
    for (int j = 0; j < 8; ++j) {
      const unsigned hb = okey16(hh[j]) >> 8;
      if (hb >= 0xC0u) atomicAdd(&hist[hb], 1);
      else if (hb == 0xBFu) ++c_bf;
    }
  }
  if (c_bf) atomicAdd(&hist[0xBF], c_bf);
  __syncthreads();

  int need = NCAND;
  unsigned prefix = 0u;
  for (int pass = 0; pass < 2; ++pass) {
    scan[tid] = hist[tid];
    __syncthreads();
    for (int off = 1; off < 256; off <<= 1) {  // inclusive suffix sum
      const int v2 = (tid + off < 256) ? scan[tid + off] : 0;
      __syncthreads();
      scan[tid] += v2;
      __syncthreads();
    }
    const int S = scan[tid];
    const int Sn = (tid < 255) ? scan[tid + 1] : 0;
    if (S >= need && Sn < need) { sel_b = tid; sel_above = Sn; }
    __syncthreads();
    need -= sel_above;
    if (pass == 0) {
      prefix = ((unsigned)sel_b) << 8;
      __syncthreads();
      hist[tid] = 0;
      __syncthreads();
      for (int i = 0; i < 8; ++i) {
        const uint4 w = *(const uint4*)(row + (size_t)((i << 8) + tid) * 8);
        const unsigned short* hh = (const unsigned short*)&w;
#pragma unroll
        for (int j = 0; j < 8; ++j) {
          const unsigned key = okey16(hh[j]);
          if ((key >> 8) == (prefix >> 8)) atomicAdd(&hist[key & 255u], 1);
        }
      }
      __syncthreads();
    } else {
      prefix |= (unsigned)sel_b;
    }
  }
  const unsigned T = prefix;
  if (tid == 0) { cnt_gt = 0; cnt_eq = 0; }
  __syncthreads();
  const int base_eq = NCAND - need;
  for (int i = 0; i < 8; ++i) {
    const int c0 = ((i << 8) + tid) * 8;
    const uint4 w = *(const uint4*)(row + c0);
    const unsigned short* hh = (const unsigned short*)&w;
#pragma unroll
    for (int j = 0; j < 8; ++j) {
      const unsigned key = okey16(hh[j]);
      if (key > T) {
        const int p = atomicAdd(&cnt_gt, 1);
        cand[tg * NCAND + p] = c0 + j;
      } else if (key == T) {
        const int p = atomicAdd(&cnt_eq, 1);
        if (p < need) cand[tg * NCAND + base_eq + p] = c0 + j;
      }
    }
  }
}

// ----------------------------------------------------------- TRANSPOSE ----
__global__ __launch_bounds__(256) void transpose_kernel(
    const float* __restrict__ W, unsigned short* __restrict__ WT) {
  __shared__ __align__(16) unsigned short tile[64][72];
  const int c0 = blockIdx.x << 6;
  const int d0 = blockIdx.y << 6;
  const int tid = threadIdx.x;
  const int r = tid >> 3;
  const int o8 = (tid & 7) << 3;
#pragma unroll
  for (int it = 0; it < 2; ++it) {
    const int d = r + it * 32;
    const float4 v0 = *(const float4*)(W + (size_t)(d0 + d) * N_CON + c0 + o8);
    const float4 v1 = *(const float4*)(W + (size_t)(d0 + d) * N_CON + c0 + o8 + 4);
    tile[d][o8 + 0] = f2b(v0.x); tile[d][o8 + 1] = f2b(v0.y);
    tile[d][o8 + 2] = f2b(v0.z); tile[d][o8 + 3] = f2b(v0.w);
    tile[d][o8 + 4] = f2b(v1.x); tile[d][o8 + 5] = f2b(v1.y);
    tile[d][o8 + 6] = f2b(v1.z); tile[d][o8 + 7] = f2b(v1.w);
  }
  __syncthreads();
#pragma unroll
  for (int it = 0; it < 2; ++it) {
    const int c = r + it * 32;
    union { unsigned short u[8]; uint4 q; } tmp;
#pragma unroll
    for (int j = 0; j < 8; ++j) tmp.u[j] = tile[o8 + j][c];
    *(uint4*)(WT + (size_t)(c0 + c) * K_DM + d0 + o8) = tmp.q;
  }
}

// ------------------------------------------------------ REFINE + DECODE ----
// 4 threads per candidate (NCAND*4 = 160 active), exact f64 dots from the
// original f32 inputs, exact top-32 with index tiebreak, then decode.
__global__ __launch_bounds__(256) void refine_decode(
    const float* __restrict__ act, const float* __restrict__ Wenc,
    const float* __restrict__ bias, const int* __restrict__ cand,
    const unsigned short* __restrict__ WT, float* __restrict__ out) {
  const int t = blockIdx.x;
  __shared__ __align__(16) float sact[K_DM];
  __shared__ double vals[NCAND];
  __shared__ int sidx[NCAND];
  __shared__ float sv[32];
  __shared__ int si[32];
  const int tid = threadIdx.x;

  *(float4*)&sact[tid * 4] = *(const float4*)(act + (size_t)t * K_DM + tid * 4);
  if (tid < NCAND) sidx[tid] = cand[t * NCAND + tid];
  __syncthreads();

  if (tid < NCAND * 4) {
    const int g = tid >> 2, i4 = (tid & 3) << 2;
    const int c = sidx[g];
    const float* wrow = Wenc + (size_t)c * K_DM;
    double s[8] = {};
    for (int q = 0; q < 64; q += 8) {
#pragma unroll
      for (int p = 0; p < 8; ++p) {
        const int e = ((q + p) << 4) + i4;
        const float4 w = *(const float4*)(wrow + e);
        const float4 a = *(const float4*)&sact[e];
        s[p] += (double)a.x * (double)w.x + (double)a.y * (double)w.y +
                (double)a.z * (double)w.z + (double)a.w * (double)w.w;
      }
    }
    double sr = ((s[0] + s[1]) + (s[2] + s[3])) + ((s[4] + s[5]) + (s[6] + s[7]));
    sr += __shfl_xor(sr, 1);
    sr += __shfl_xor(sr, 2);
    if ((tid & 3) == 0) vals[g] = sr + (double)bias[c];
  }
  __syncthreads();

  if (tid < NCAND) {
    const double v = vals[tid];
    const int ci = sidx[tid];
    int rank = 0;
    for (int j = 0; j < NCAND; ++j) {
      const double vj = vals[j];
      if (vj > v || (vj == v && sidx[j] < ci)) ++rank;
    }
    if (rank < 32) { sv[rank] = (float)v; si[rank] = ci; }
  }
  __syncthreads();

  const int d4 = tid << 2;
  float a0 = 0.f, a1 = 0.f, a2 = 0.f, a3 = 0.f;
#pragma unroll
  for (int j = 0; j < 32; ++j) {
    const float v = sv[j];
    const ushort4 w = *(const ushort4*)(WT + (size_t)si[j] * K_DM + d4);
    a0 += v * b2f(w.x); a1 += v * b2f(w.y);
    a2 += v * b2f(w.z); a3 += v * b2f(w.w);
  }
  float4 o; o.x = a0; o.y = a1; o.z = a2; o.w = a3;
  *(float4*)(out + (size_t)t * K_DM + d4) = o;
}

extern "C" void kernel_launch(void* const* d_in, const int* in_sizes, int n_in,
                              void* d_out, int out_size, void* d_ws, size_t ws_size,
                              hipStream_t stream) {
  const float* act  = (const float*)d_in[0];  // [4096][1024]
  const float* Wenc = (const float*)d_in[1];  // [16384][1024]
  const float* bias = (const float*)d_in[2];  // [16384]
  const float* Wemb = (const float*)d_in[3];  // [1024][16384]
  (void)in_sizes; (void)n_in; (void)out_size;
  float* out = (float*)d_out;

  char* ws = (char*)d_ws;
  unsigned short* Bhi = (unsigned short*)ws;                  // 33,554,432
  unsigned short* Ahi = (unsigned short*)(ws + 33554432ull);  //  8,388,608
  int* cand           = (int*)(ws + 41943040ull);             //  1,048,576 (need 655,360)
  const size_t PRE_OFF = 42991616ull;
  unsigned short* pre = (unsigned short*)(ws + PRE_OFF);
  unsigned short* WT  = (unsigned short*)ws;  // aliases Bhi after last gemm

  int chunk = 256, m_bits = 1;
  if (ws_size >= PRE_OFF + 33554432ull) { chunk = 1024; m_bits = 3; }
  else if (ws_size >= PRE_OFF + 16777216ull) { chunk = 512; m_bits = 2; }

  split_kernel<<<dim3(20480), dim3(256), 0, stream>>>(act, Wenc, Ahi, Bhi);

  for (int tok0 = 0; tok0 < M_TOK; tok0 += chunk) {
    const int grid = (chunk / 128) * (N_CON / 128);
    gemm_bf16<<<dim3(grid), dim3(256), 0, stream>>>(
        Ahi + (size_t)tok0 * K_DM, Bhi, bias, pre, m_bits);
    cand_kernel<<<dim3(chunk), dim3(256), 0, stream>>>(pre, cand, tok0);
  }

  transpose_kernel<<<dim3(N_CON / 64, K_DM / 64), dim3(256), 0, stream>>>(Wemb, WT);
  refine_decode<<<dim3(M_TOK), dim3(256), 0, stream>>>(act, Wenc, bias, cand, WT, out);
}